// Round 6
// baseline (570.083 us; speedup 1.0000x reference)
//
#include <hip/hip_runtime.h>
#include <hip/hip_fp16.h>
#include <stdint.h>

#define V_N   50257
#define NPAN  393                    // ceil(V_N/128)
#define V_PAD (NPAN * 128)           // 50304
#define NCH   1024
#define MT    4096                   // B*S
#define KC    512                    // 2*N_FREQ
#define NFRQ  256
#define TWO_PI 6.28318530717958647692f

typedef _Float16 f16;
typedef __attribute__((ext_vector_type(8))) _Float16 f16x8;
typedef __attribute__((ext_vector_type(4))) float    f32x4;

// async global->LDS, 16B per lane; LDS dest = wave-uniform base + lane*16
__device__ __forceinline__ void gload_lds16(const void* g, const void* l) {
  typedef const __attribute__((address_space(1))) unsigned int* gp_t;
  typedef __attribute__((address_space(3))) unsigned int* lp_t;
  __builtin_amdgcn_global_load_lds((gp_t)(uint64_t)(uintptr_t)g,
                                   (lp_t)(uint32_t)(uintptr_t)l, 16, 0, 0);
}

// ---------------- Kernel 0: B_ws[t][k] trig table, t-major ---------------------------
__global__ __launch_bounds__(256) void k0_genB(f16* __restrict__ B) {
  int gid = blockIdx.x * 256 + threadIdx.x;
  int t = gid >> 6, q = gid & 63;
  if (t >= V_PAD) return;
  f16x8 pk;
  if (t < V_N) {
    const float w0 = TWO_PI / (float)V_N;
#pragma unroll
    for (int p = 0; p < 4; ++p) {
      int f = 4 * q + p + 1;
      int m = (f * t) % V_N;
      float sn, cs;
      __sincosf(w0 * (float)m, &sn, &cs);
      pk[2 * p]     = (f16)cs;
      pk[2 * p + 1] = (f16)(-sn);
    }
  } else {
#pragma unroll
    for (int j = 0; j < 8; ++j) pk[j] = (f16)0.f;
  }
  *(f16x8*)&B[(size_t)t * KC + q * 8] = pk;
}

// ---------------- Kernel 1: A[m][2f+e] = (e? Yi : Yr)[m][f],  Y = h @ w -------------
__global__ __launch_bounds__(256) void k1_proj(
    const float* __restrict__ h, const float* __restrict__ w, f16* __restrict__ A) {
  __shared__ __align__(16) f16 As[64 * 64];
  __shared__ __align__(16) f16 Bs[64 * 64];
  const int tid = threadIdx.x;
  const int bn0 = blockIdx.x * 64;
  const int bm0 = blockIdx.y * 64;
  const int lane = tid & 63, wid = tid >> 6;
  const int lr = lane & 15, lg = lane >> 4;
  const int wr = wid >> 1, wc = wid & 1;

  f32x4 acc[2][2];
#pragma unroll
  for (int i = 0; i < 2; ++i)
#pragma unroll
    for (int j = 0; j < 2; ++j) acc[i][j] = (f32x4){0.f, 0.f, 0.f, 0.f};

  for (int s = 0; s < NCH / 64; ++s) {
    const int k0 = s * 64;
    __syncthreads();
#pragma unroll
    for (int r = 0; r < 2; ++r) {
      int q = tid + r * 256;
      int m = q >> 3, c = q & 7;
      const float* src = h + (size_t)(bm0 + m) * NCH + k0 + c * 8;
      f32x4 v0 = *(const f32x4*)src;
      f32x4 v1 = *(const f32x4*)(src + 4);
      f16x8 pk;
#pragma unroll
      for (int e = 0; e < 4; ++e) { pk[e] = (f16)v0[e]; pk[4 + e] = (f16)v1[e]; }
      *(f16x8*)&As[m * 64 + ((c ^ (m & 7)) << 3)] = pk;
    }
#pragma unroll
    for (int r = 0; r < 2; ++r) {
      int q = tid + r * 256;
      int c = q >> 6, n = q & 63;
      int jj = bn0 + n;
      int wcol = (jj >> 1) + ((jj & 1) ? NFRQ : 0);
      f16x8 pk;
#pragma unroll
      for (int j = 0; j < 8; ++j)
        pk[j] = (f16)w[(size_t)(k0 + c * 8 + j) * KC + wcol];
      *(f16x8*)&Bs[n * 64 + ((c ^ (n & 7)) << 3)] = pk;
    }
    __syncthreads();
#pragma unroll
    for (int kk = 0; kk < 2; ++kk) {
      const int cb = kk * 4 + lg;
      f16x8 a[2], b[2];
#pragma unroll
      for (int mi = 0; mi < 2; ++mi) {
        int row = wr * 32 + mi * 16 + lr;
        a[mi] = *(const f16x8*)&As[row * 64 + ((cb ^ (row & 7)) << 3)];
      }
#pragma unroll
      for (int ni = 0; ni < 2; ++ni) {
        int col = wc * 32 + ni * 16 + lr;
        b[ni] = *(const f16x8*)&Bs[col * 64 + ((cb ^ (col & 7)) << 3)];
      }
#pragma unroll
      for (int mi = 0; mi < 2; ++mi)
#pragma unroll
        for (int ni = 0; ni < 2; ++ni)
          acc[mi][ni] = __builtin_amdgcn_mfma_f32_16x16x32_f16(a[mi], b[ni], acc[mi][ni], 0, 0, 0);
    }
  }
#pragma unroll
  for (int mi = 0; mi < 2; ++mi)
#pragma unroll
    for (int ni = 0; ni < 2; ++ni)
#pragma unroll
      for (int r = 0; r < 4; ++r) {
        int row = bm0 + wr * 32 + mi * 16 + lg * 4 + r;
        int col = bn0 + wc * 32 + ni * 16 + lr;
        A[(size_t)row * KC + col] = (f16)acc[mi][ni][r];
      }
}

// ---------------- Kernel 2: 128x128, 4 waves, BK=64, 2-phase dbuf, counted vmcnt -----
// 64 KB LDS -> 2 blocks/CU: two independent barrier groups per CU so one block's
// vmcnt/lgkm/barrier stalls are covered by the other block's compute (the R5 theory).
// One vmcnt(8) per tile (full-tile lead, 8 gloads/wave in flight), 2 raw barriers.

__device__ __forceinline__ void stage_tile(const f16* __restrict__ M, int grow0,
                                           int kt, f16* dst, int wid, int lane) {
#pragma unroll
  for (int i = 0; i < 4; ++i) {
    int idx = wid * 4 + i;
    int q = idx * 64 + lane;
    int m = q >> 3, c = q & 7;
    int cg = c ^ (m & 7);                       // source-side swizzle (rule #21)
    gload_lds16(M + (size_t)(grow0 + m) * KC + kt * 64 + cg * 8, dst + idx * 512);
  }
}

__device__ __forceinline__ void compute_tile(
    const f16* __restrict__ CA, const f16* __restrict__ CB,
    int wr, int wc, int lr, int lg, f32x4 acc[4][4]) {
#pragma unroll
  for (int kk = 0; kk < 2; ++kk) {
    const int cb = kk * 4 + lg;
    f16x8 a[4], b[4];
#pragma unroll
    for (int mi = 0; mi < 4; ++mi) {
      int row = wr * 64 + mi * 16 + lr;
      a[mi] = *(const f16x8*)&CA[row * 64 + ((cb ^ (row & 7)) << 3)];
    }
#pragma unroll
    for (int ni = 0; ni < 4; ++ni) {
      int col = wc * 64 + ni * 16 + lr;
      b[ni] = *(const f16x8*)&CB[col * 64 + ((cb ^ (col & 7)) << 3)];
    }
    __builtin_amdgcn_s_setprio(1);
#pragma unroll
    for (int mi = 0; mi < 4; ++mi)
#pragma unroll
      for (int ni = 0; ni < 4; ++ni)
        acc[mi][ni] = __builtin_amdgcn_mfma_f32_16x16x32_f16(a[mi], b[ni], acc[mi][ni], 0, 0, 0);
    __builtin_amdgcn_s_setprio(0);
  }
}

__global__ __launch_bounds__(256, 2) void k2_2ph(
    const f16* __restrict__ A, const f16* __restrict__ B, float* __restrict__ out) {
  __shared__ __align__(16) f16 As0[128 * 64], As1[128 * 64];
  __shared__ __align__(16) f16 Bs0[128 * 64], Bs1[128 * 64];
  const int tid = threadIdx.x;
  // XCD-aware bijective swizzle: nwg = 12576 = 8 * 1572; panel-major (32 m per panel)
  const int orig = blockIdx.x;
  const int wgid = (orig & 7) * 1572 + (orig >> 3);
  const int bx = wgid >> 5;          // 0..392 (n panel)
  const int by = wgid & 31;          // 0..31  (m panel)
  const int bn0 = bx << 7;
  const int bm0 = by << 7;
  const int lane = tid & 63, wid = tid >> 6;
  const int lr = lane & 15, lg = lane >> 4;
  const int wr = wid >> 1, wc = wid & 1;

  f32x4 acc[4][4];
#pragma unroll
  for (int i = 0; i < 4; ++i)
#pragma unroll
    for (int j = 0; j < 4; ++j) acc[i][j] = (f32x4){0.f, 0.f, 0.f, 0.f};

  // prologue: stage tile 0 into buf0
  stage_tile(A, bm0, 0, As0, wid, lane);
  stage_tile(B, bn0, 0, Bs0, wid, lane);

  for (int t2 = 0; t2 < 8; t2 += 2) {
    // ---- tile t2: CUR = buf0, stage t2+1 -> buf1 ----
    stage_tile(A, bm0, t2 + 1, As1, wid, lane);
    stage_tile(B, bn0, t2 + 1, Bs1, wid, lane);
    asm volatile("s_waitcnt vmcnt(8)" ::: "memory");   // buf0's 8 loads done
    __builtin_amdgcn_s_barrier();
    compute_tile(As0, Bs0, wr, wc, lr, lg, acc);
    __builtin_amdgcn_s_barrier();
    // ---- tile t2+1: CUR = buf1, stage t2+2 -> buf0 ----
    if (t2 < 6) {
      stage_tile(A, bm0, t2 + 2, As0, wid, lane);
      stage_tile(B, bn0, t2 + 2, Bs0, wid, lane);
      asm volatile("s_waitcnt vmcnt(8)" ::: "memory");
    } else {
      asm volatile("s_waitcnt vmcnt(0)" ::: "memory");
    }
    __builtin_amdgcn_s_barrier();
    compute_tile(As1, Bs1, wr, wc, lr, lg, acc);
    __builtin_amdgcn_s_barrier();
  }

  const float scale = 2.0f / (float)V_N;
#pragma unroll
  for (int ni = 0; ni < 4; ++ni) {
    int col = bn0 + wc * 64 + ni * 16 + lr;
    if (col < V_N) {
#pragma unroll
      for (int mi = 0; mi < 4; ++mi)
#pragma unroll
        for (int r = 0; r < 4; ++r) {
          int row = bm0 + wr * 64 + mi * 16 + lg * 4 + r;
          out[(size_t)row * V_N + col] = acc[mi][ni][r] * scale;
        }
    }
  }
}

// ---------------- Fallback kernel 2: on-the-fly B generation (R0, proven) ------------
__global__ __launch_bounds__(256) void k2_synth_otf(
    const f16* __restrict__ A, float* __restrict__ out) {
  __shared__ __align__(16) f16 As[128 * 64];
  __shared__ __align__(16) f16 Bs[128 * 64];
  const int tid = threadIdx.x;
  const int bn0 = blockIdx.x * 128;
  const int bm0 = blockIdx.y * 128;
  const int lane = tid & 63, wid = tid >> 6;
  const int lr = lane & 15, lg = lane >> 4;
  const int wr = wid >> 1, wc = wid & 1;

  const int nloc = tid & 127;
  const int g = tid >> 7;
  const int t = bn0 + nloc;
  const float w0 = TWO_PI / (float)V_N;
  float cr, ci, r1c, r1s, r17c, r17s;
  {
    int a1 = (int)(((long long)(16 * g + 1) * t) % V_N);
    int a2 = (int)((long long)t % V_N);
    int a3 = (int)(((long long)17 * t) % V_N);
    __sincosf((float)a1 * w0, &ci, &cr);
    __sincosf((float)a2 * w0, &r1s, &r1c);
    __sincosf((float)a3 * w0, &r17s, &r17c);
  }

  f32x4 acc[4][4];
#pragma unroll
  for (int i = 0; i < 4; ++i)
#pragma unroll
    for (int j = 0; j < 4; ++j) acc[i][j] = (f32x4){0.f, 0.f, 0.f, 0.f};

  for (int s = 0; s < KC / 64; ++s) {
    f16x8 bch[4];
#pragma unroll
    for (int u = 0; u < 4; ++u)
#pragma unroll
      for (int p = 0; p < 4; ++p) {
        bch[u][2 * p]     = (f16)cr;
        bch[u][2 * p + 1] = (f16)(-ci);
        float rc = (u == 3 && p == 3) ? r17c : r1c;
        float rs = (u == 3 && p == 3) ? r17s : r1s;
        float nc = cr * rc - ci * rs;
        float ns = cr * rs + ci * rc;
        cr = nc; ci = ns;
      }
    __syncthreads();
#pragma unroll
    for (int ii = 0; ii < 4; ++ii) {
      int i = wid * 4 + ii;
      int q = i * 64 + lane;
      int m = q >> 3, cl = q & 7;
      int cg = cl ^ (m & 7);
      gload_lds16(A + (size_t)(bm0 + m) * KC + s * 64 + cg * 8, &As[i * 512]);
    }
#pragma unroll
    for (int u = 0; u < 4; ++u) {
      int c = 4 * g + u;
      *(f16x8*)&Bs[nloc * 64 + ((c ^ (nloc & 7)) << 3)] = bch[u];
    }
    __syncthreads();
#pragma unroll
    for (int kk = 0; kk < 2; ++kk) {
      const int cb = kk * 4 + lg;
      f16x8 av[4], bv[4];
#pragma unroll
      for (int mi = 0; mi < 4; ++mi) {
        int row = wr * 64 + mi * 16 + lr;
        av[mi] = *(const f16x8*)&As[row * 64 + ((cb ^ (row & 7)) << 3)];
      }
#pragma unroll
      for (int ni = 0; ni < 4; ++ni) {
        int col = wc * 64 + ni * 16 + lr;
        bv[ni] = *(const f16x8*)&Bs[col * 64 + ((cb ^ (col & 7)) << 3)];
      }
#pragma unroll
      for (int mi = 0; mi < 4; ++mi)
#pragma unroll
        for (int ni = 0; ni < 4; ++ni)
          acc[mi][ni] = __builtin_amdgcn_mfma_f32_16x16x32_f16(av[mi], bv[ni], acc[mi][ni], 0, 0, 0);
    }
  }
  const float scale = 2.0f / (float)V_N;
#pragma unroll
  for (int ni = 0; ni < 4; ++ni) {
    int col = bn0 + wc * 64 + ni * 16 + lr;
    if (col < V_N) {
#pragma unroll
      for (int mi = 0; mi < 4; ++mi)
#pragma unroll
        for (int r = 0; r < 4; ++r) {
          int row = bm0 + wr * 64 + mi * 16 + lg * 4 + r;
          out[(size_t)row * V_N + col] = acc[mi][ni][r] * scale;
        }
    }
  }
}

extern "C" void kernel_launch(void* const* d_in, const int* in_sizes, int n_in,
                              void* d_out, int out_size, void* d_ws, size_t ws_size,
                              hipStream_t stream) {
  const float* h = (const float*)d_in[0];
  const float* w = (const float*)d_in[1];
  float* out = (float*)d_out;

  const size_t B_BYTES = (size_t)V_PAD * KC * sizeof(f16);   // 51.5 MB
  const size_t A_BYTES = (size_t)MT * KC * sizeof(f16);      //  4.2 MB
  dim3 blk(256);

  if (ws_size >= B_BYTES + A_BYTES) {
    f16* Bt = (f16*)d_ws;
    f16* A  = (f16*)((char*)d_ws + B_BYTES);
    hipLaunchKernelGGL(k0_genB, dim3((V_PAD * 64) / 256), blk, 0, stream, Bt);
    hipLaunchKernelGGL(k1_proj, dim3(KC / 64, MT / 64), blk, 0, stream, h, w, A);
    hipLaunchKernelGGL(k2_2ph, dim3(NPAN * 32), blk, 0, stream, A, Bt, out);
  } else {
    f16* A = (f16*)d_ws;
    hipLaunchKernelGGL(k1_proj, dim3(KC / 64, MT / 64), blk, 0, stream, h, w, A);
    hipLaunchKernelGGL(k2_synth_otf, dim3((V_N + 127) / 128, MT / 128), blk, 0, stream, A, out);
  }
}

// Round 8
// 384.251 us; speedup vs baseline: 1.4836x; 1.4836x over previous
//
#include <hip/hip_runtime.h>
#include <hip/hip_fp16.h>
#include <stdint.h>

#define V_N   50257
#define NPAN  393                    // ceil(V_N/128)
#define NCH   1024
#define MT    4096                   // B*S
#define KC    512                    // 2*N_FREQ
#define NFRQ  256
#define TWO_PI 6.28318530717958647692f

typedef _Float16 f16;
typedef __attribute__((ext_vector_type(8))) _Float16 f16x8;
typedef __attribute__((ext_vector_type(4))) float    f32x4;

// async global->LDS, 16B per lane; LDS dest = wave-uniform base + lane*16
__device__ __forceinline__ void gload_lds16(const void* g, const void* l) {
  typedef const __attribute__((address_space(1))) unsigned int* gp_t;
  typedef __attribute__((address_space(3))) unsigned int* lp_t;
  __builtin_amdgcn_global_load_lds((gp_t)(uint64_t)(uintptr_t)g,
                                   (lp_t)(uint32_t)(uintptr_t)l, 16, 0, 0);
}

// ---------------- Kernel 1: A[m][2f+e] = (e? Yi : Yr)[m][f],  Y = h @ w -------------
__global__ __launch_bounds__(256) void k1_proj(
    const float* __restrict__ h, const float* __restrict__ w, f16* __restrict__ A) {
  __shared__ __align__(16) f16 As[64 * 64];
  __shared__ __align__(16) f16 Bs[64 * 64];
  const int tid = threadIdx.x;
  const int bn0 = blockIdx.x * 64;
  const int bm0 = blockIdx.y * 64;
  const int lane = tid & 63, wid = tid >> 6;
  const int lr = lane & 15, lg = lane >> 4;
  const int wr = wid >> 1, wc = wid & 1;

  f32x4 acc[2][2];
#pragma unroll
  for (int i = 0; i < 2; ++i)
#pragma unroll
    for (int j = 0; j < 2; ++j) acc[i][j] = (f32x4){0.f, 0.f, 0.f, 0.f};

  for (int s = 0; s < NCH / 64; ++s) {
    const int k0 = s * 64;
    __syncthreads();
#pragma unroll
    for (int r = 0; r < 2; ++r) {
      int q = tid + r * 256;
      int m = q >> 3, c = q & 7;
      const float* src = h + (size_t)(bm0 + m) * NCH + k0 + c * 8;
      f32x4 v0 = *(const f32x4*)src;
      f32x4 v1 = *(const f32x4*)(src + 4);
      f16x8 pk;
#pragma unroll
      for (int e = 0; e < 4; ++e) { pk[e] = (f16)v0[e]; pk[4 + e] = (f16)v1[e]; }
      *(f16x8*)&As[m * 64 + ((c ^ (m & 7)) << 3)] = pk;
    }
#pragma unroll
    for (int r = 0; r < 2; ++r) {
      int q = tid + r * 256;
      int c = q >> 6, n = q & 63;
      int jj = bn0 + n;
      int wcol = (jj >> 1) + ((jj & 1) ? NFRQ : 0);
      f16x8 pk;
#pragma unroll
      for (int j = 0; j < 8; ++j)
        pk[j] = (f16)w[(size_t)(k0 + c * 8 + j) * KC + wcol];
      *(f16x8*)&Bs[n * 64 + ((c ^ (n & 7)) << 3)] = pk;
    }
    __syncthreads();
#pragma unroll
    for (int kk = 0; kk < 2; ++kk) {
      const int cb = kk * 4 + lg;
      f16x8 a[2], b[2];
#pragma unroll
      for (int mi = 0; mi < 2; ++mi) {
        int row = wr * 32 + mi * 16 + lr;
        a[mi] = *(const f16x8*)&As[row * 64 + ((cb ^ (row & 7)) << 3)];
      }
#pragma unroll
      for (int ni = 0; ni < 2; ++ni) {
        int col = wc * 32 + ni * 16 + lr;
        b[ni] = *(const f16x8*)&Bs[col * 64 + ((cb ^ (col & 7)) << 3)];
      }
#pragma unroll
      for (int mi = 0; mi < 2; ++mi)
#pragma unroll
        for (int ni = 0; ni < 2; ++ni)
          acc[mi][ni] = __builtin_amdgcn_mfma_f32_16x16x32_f16(a[mi], b[ni], acc[mi][ni], 0, 0, 0);
    }
  }
#pragma unroll
  for (int mi = 0; mi < 2; ++mi)
#pragma unroll
    for (int ni = 0; ni < 2; ++ni)
#pragma unroll
      for (int r = 0; r < 4; ++r) {
        int row = bm0 + wr * 32 + mi * 16 + lg * 4 + r;
        int col = bn0 + wc * 32 + ni * 16 + lr;
        A[(size_t)row * KC + col] = (f16)acc[mi][ni][r];
      }
}

// ---------------- Kernel 2: OTF-B (zero B memory traffic), EXACT-seeded B-gen --------
// 128x128 tile, 4 waves, BK=64, A dbuf via gload_lds + counted vmcnt(4),
// B dbuf in LDS. B-gen numerics == the PASSING k0_genB path: T[j] and per-tile base
// both from exact integer-reduced sincos; bch = base*T[j] (one mult deep, ~3e-7).

__device__ __forceinline__ void stage_tile(const f16* __restrict__ M, int grow0,
                                           int kt, f16* dst, int wid, int lane) {
#pragma unroll
  for (int i = 0; i < 4; ++i) {
    int idx = wid * 4 + i;
    int q = idx * 64 + lane;
    int m = q >> 3, c = q & 7;
    int cg = c ^ (m & 7);                       // source-side swizzle (rule #21)
    gload_lds16(M + (size_t)(grow0 + m) * KC + kt * 64 + cg * 8, dst + idx * 512);
  }
}

__device__ __forceinline__ void compute_tile(
    const f16* __restrict__ CA, const f16* __restrict__ CB,
    int wr, int wc, int lr, int lg, f32x4 acc[4][4]) {
#pragma unroll
  for (int kk = 0; kk < 2; ++kk) {
    const int cb = kk * 4 + lg;
    f16x8 a[4], b[4];
#pragma unroll
    for (int mi = 0; mi < 4; ++mi) {
      int row = wr * 64 + mi * 16 + lr;
      a[mi] = *(const f16x8*)&CA[row * 64 + ((cb ^ (row & 7)) << 3)];
    }
#pragma unroll
    for (int ni = 0; ni < 4; ++ni) {
      int col = wc * 64 + ni * 16 + lr;
      b[ni] = *(const f16x8*)&CB[col * 64 + ((cb ^ (col & 7)) << 3)];
    }
    __builtin_amdgcn_s_setprio(1);
#pragma unroll
    for (int mi = 0; mi < 4; ++mi)
#pragma unroll
      for (int ni = 0; ni < 4; ++ni)
        acc[mi][ni] = __builtin_amdgcn_mfma_f32_16x16x32_f16(a[mi], b[ni], acc[mi][ni], 0, 0, 0);
    __builtin_amdgcn_s_setprio(0);
  }
}

// base = e^{i*w0*((32s+16g)*t mod V)} — exact integer reduction, no chaining
__device__ __forceinline__ void seed_base(int s, int g, int t, float& br, float& bi) {
  int fb = 32 * s + 16 * g;
  int m = (fb * t) % V_N;                        // fb*t <= 480*50302 < 2^31
  float sn, cs;
  __sincosf((TWO_PI / (float)V_N) * (float)m, &sn, &cs);
  br = cs; bi = sn;
}

__device__ __forceinline__ void gen_bt(const float Tr[16], const float Ti[16],
                                       float br, float bi, f16x8 bt[4]) {
#pragma unroll
  for (int u = 0; u < 4; ++u)
#pragma unroll
    for (int p = 0; p < 4; ++p) {
      const int j = 4 * u + p;
      float re = br * Tr[j] - bi * Ti[j];      // cos(w0*(fb+j+1)*t)
      float im = br * Ti[j] + bi * Tr[j];      // sin(...)
      bt[u][2 * p]     = (f16)re;
      bt[u][2 * p + 1] = (f16)(-im);
    }
}

__device__ __forceinline__ void store_bt(f16* Bs, int nloc, int g, const f16x8 bt[4]) {
#pragma unroll
  for (int u = 0; u < 4; ++u) {
    int c = 4 * g + u;
    *(f16x8*)&Bs[nloc * 64 + ((c ^ (nloc & 7)) << 3)] = bt[u];
  }
}

__global__ __launch_bounds__(256, 2) void k2_otf3(
    const f16* __restrict__ A, float* __restrict__ out) {
  __shared__ __align__(16) f16 As0[128 * 64], As1[128 * 64];
  __shared__ __align__(16) f16 Bs0[128 * 64], Bs1[128 * 64];
  const int tid = threadIdx.x;
  // XCD bijective swizzle (12576 = 8*1572) + by-MAJOR: each XCD owns exactly 4
  // m-panels (1572 = 4*393) -> A L2-resident; adjacent-bx blocks co-resident so
  // partial 128B out-lines merge in L2 before eviction.
  const int orig = blockIdx.x;
  const int wgid = (orig & 7) * 1572 + (orig >> 3);
  const int by = wgid / 393;
  const int bx = wgid - by * 393;
  const int bn0 = bx << 7;
  const int bm0 = by << 7;
  const int lane = tid & 63, wid = tid >> 6;
  const int lr = lane & 15, lg = lane >> 4;
  const int wr = wid >> 1, wc = wid & 1;

  // ---- B-gen init: T[j] = e^{i*w0*((j+1)t mod V)}, all exact-seeded ----
  const int nloc = tid & 127;
  const int g = tid >> 7;
  int t = bn0 + nloc;
  if (t >= V_N) t -= V_N;                       // tail cols alias; never written
  const float w0 = TWO_PI / (float)V_N;
  float Tr[16], Ti[16];
#pragma unroll
  for (int j = 0; j < 16; ++j) {
    int m = ((j + 1) * t) % V_N;
    float sn, cs;
    __sincosf(w0 * (float)m, &sn, &cs);
    Tr[j] = cs; Ti[j] = sn;
  }

  f32x4 acc[4][4];
#pragma unroll
  for (int i = 0; i < 4; ++i)
#pragma unroll
    for (int j = 0; j < 4; ++j) acc[i][j] = (f32x4){0.f, 0.f, 0.f, 0.f};

  // ---- prologue: B(0) -> Bs0, A(0) -> As0 ----
  {
    float br, bi;
    seed_base(0, g, t, br, bi);
    f16x8 bt[4];
    gen_bt(Tr, Ti, br, bi, bt);
    store_bt(Bs0, nloc, g, bt);
  }
  stage_tile(A, bm0, 0, As0, wid, lane);

  for (int s = 0; s < 8; ++s) {
    const bool nxt = (s < 7);
    f16* Ac = (s & 1) ? As1 : As0;
    f16* An = (s & 1) ? As0 : As1;
    f16* Bc = (s & 1) ? Bs1 : Bs0;
    f16* Bn = (s & 1) ? Bs0 : Bs1;
    if (nxt) {
      stage_tile(A, bm0, s + 1, An, wid, lane);  // 4 gloads in flight
      float br, bi;
      seed_base(s + 1, g, t, br, bi);            // exact seed, no chaining
      f16x8 bt[4];
      gen_bt(Tr, Ti, br, bi, bt);                // VALU overlaps gload latency
      store_bt(Bn, nloc, g, bt);
    }
    asm volatile("s_waitcnt lgkmcnt(0)" ::: "memory");   // own B writes drained
    if (nxt) asm volatile("s_waitcnt vmcnt(4)" ::: "memory");  // A(s) landed
    else     asm volatile("s_waitcnt vmcnt(0)" ::: "memory");
    __builtin_amdgcn_s_barrier();
    compute_tile(Ac, Bc, wr, wc, lr, lg, acc);
    asm volatile("" ::: "memory");
    __builtin_amdgcn_s_barrier();
  }

  const float scale = 2.0f / (float)V_N;
#pragma unroll
  for (int ni = 0; ni < 4; ++ni) {
    int col = bn0 + wc * 64 + ni * 16 + lr;
    if (col < V_N) {
#pragma unroll
      for (int mi = 0; mi < 4; ++mi)
#pragma unroll
        for (int r = 0; r < 4; ++r) {
          int row = bm0 + wr * 64 + mi * 16 + lg * 4 + r;
          out[(size_t)row * V_N + col] = acc[mi][ni][r] * scale;
        }
    }
  }
}

extern "C" void kernel_launch(void* const* d_in, const int* in_sizes, int n_in,
                              void* d_out, int out_size, void* d_ws, size_t ws_size,
                              hipStream_t stream) {
  const float* h = (const float*)d_in[0];
  const float* w = (const float*)d_in[1];
  float* out = (float*)d_out;
  f16* A = (f16*)d_ws;                           // MT*KC*2 = 4.2 MB scratch

  dim3 blk(256);
  hipLaunchKernelGGL(k1_proj, dim3(KC / 64, MT / 64), blk, 0, stream, h, w, A);
  hipLaunchKernelGGL(k2_otf3, dim3(NPAN * 32), blk, 0, stream, A, out);
}

// Round 9
// 372.861 us; speedup vs baseline: 1.5289x; 1.0305x over previous
//
#include <hip/hip_runtime.h>
#include <hip/hip_fp16.h>
#include <stdint.h>

#define V_N   50257
#define NPAN  393                    // ceil(V_N/128)
#define NCH   1024
#define MT    4096                   // B*S
#define KC    512                    // 2*N_FREQ
#define NFRQ  256
#define TWO_PI 6.28318530717958647692f

typedef _Float16 f16;
typedef __attribute__((ext_vector_type(8))) _Float16 f16x8;
typedef __attribute__((ext_vector_type(4))) float    f32x4;

// async global->LDS, 16B per lane; LDS dest = wave-uniform base + lane*16
__device__ __forceinline__ void gload_lds16(const void* g, const void* l) {
  typedef const __attribute__((address_space(1))) unsigned int* gp_t;
  typedef __attribute__((address_space(3))) unsigned int* lp_t;
  __builtin_amdgcn_global_load_lds((gp_t)(uint64_t)(uintptr_t)g,
                                   (lp_t)(uint32_t)(uintptr_t)l, 16, 0, 0);
}

// ---------------- Kernel 1: A[m][2f+e] = (e? Yi : Yr)[m][f],  Y = h @ w -------------
__global__ __launch_bounds__(256) void k1_proj(
    const float* __restrict__ h, const float* __restrict__ w, f16* __restrict__ A) {
  __shared__ __align__(16) f16 As[64 * 64];
  __shared__ __align__(16) f16 Bs[64 * 64];
  const int tid = threadIdx.x;
  const int bn0 = blockIdx.x * 64;
  const int bm0 = blockIdx.y * 64;
  const int lane = tid & 63, wid = tid >> 6;
  const int lr = lane & 15, lg = lane >> 4;
  const int wr = wid >> 1, wc = wid & 1;

  f32x4 acc[2][2];
#pragma unroll
  for (int i = 0; i < 2; ++i)
#pragma unroll
    for (int j = 0; j < 2; ++j) acc[i][j] = (f32x4){0.f, 0.f, 0.f, 0.f};

  for (int s = 0; s < NCH / 64; ++s) {
    const int k0 = s * 64;
    __syncthreads();
#pragma unroll
    for (int r = 0; r < 2; ++r) {
      int q = tid + r * 256;
      int m = q >> 3, c = q & 7;
      const float* src = h + (size_t)(bm0 + m) * NCH + k0 + c * 8;
      f32x4 v0 = *(const f32x4*)src;
      f32x4 v1 = *(const f32x4*)(src + 4);
      f16x8 pk;
#pragma unroll
      for (int e = 0; e < 4; ++e) { pk[e] = (f16)v0[e]; pk[4 + e] = (f16)v1[e]; }
      *(f16x8*)&As[m * 64 + ((c ^ (m & 7)) << 3)] = pk;
    }
#pragma unroll
    for (int r = 0; r < 2; ++r) {
      int q = tid + r * 256;
      int c = q >> 6, n = q & 63;
      int jj = bn0 + n;
      int wcol = (jj >> 1) + ((jj & 1) ? NFRQ : 0);
      f16x8 pk;
#pragma unroll
      for (int j = 0; j < 8; ++j)
        pk[j] = (f16)w[(size_t)(k0 + c * 8 + j) * KC + wcol];
      *(f16x8*)&Bs[n * 64 + ((c ^ (n & 7)) << 3)] = pk;
    }
    __syncthreads();
#pragma unroll
    for (int kk = 0; kk < 2; ++kk) {
      const int cb = kk * 4 + lg;
      f16x8 a[2], b[2];
#pragma unroll
      for (int mi = 0; mi < 2; ++mi) {
        int row = wr * 32 + mi * 16 + lr;
        a[mi] = *(const f16x8*)&As[row * 64 + ((cb ^ (row & 7)) << 3)];
      }
#pragma unroll
      for (int ni = 0; ni < 2; ++ni) {
        int col = wc * 32 + ni * 16 + lr;
        b[ni] = *(const f16x8*)&Bs[col * 64 + ((cb ^ (col & 7)) << 3)];
      }
#pragma unroll
      for (int mi = 0; mi < 2; ++mi)
#pragma unroll
        for (int ni = 0; ni < 2; ++ni)
          acc[mi][ni] = __builtin_amdgcn_mfma_f32_16x16x32_f16(a[mi], b[ni], acc[mi][ni], 0, 0, 0);
    }
  }
#pragma unroll
  for (int mi = 0; mi < 2; ++mi)
#pragma unroll
    for (int ni = 0; ni < 2; ++ni)
#pragma unroll
      for (int r = 0; r < 4; ++r) {
        int row = bm0 + wr * 32 + mi * 16 + lg * 4 + r;
        int col = bn0 + wc * 32 + ni * 16 + lr;
        A[(size_t)row * KC + col] = (f16)acc[mi][ni][r];
      }
}

// ---------------- Kernel 2: OTF-B, single B buffer (write-after-read), 3 blocks/CU ---
// 128x128 tile, 4 waves, BK=64. A dbuf via gload_lds + counted vmcnt(4).
// B: next tile generated into REGISTERS pre-barrier, ds_written AFTER the
// post-compute barrier into the single 16KB buffer. LDS = 48KB -> 3 blocks/CU.

__device__ __forceinline__ void stage_tile(const f16* __restrict__ M, int grow0,
                                           int kt, f16* dst, int wid, int lane) {
#pragma unroll
  for (int i = 0; i < 4; ++i) {
    int idx = wid * 4 + i;
    int q = idx * 64 + lane;
    int m = q >> 3, c = q & 7;
    int cg = c ^ (m & 7);                       // source-side swizzle (rule #21)
    gload_lds16(M + (size_t)(grow0 + m) * KC + kt * 64 + cg * 8, dst + idx * 512);
  }
}

__device__ __forceinline__ void compute_tile(
    const f16* __restrict__ CA, const f16* __restrict__ CB,
    int wr, int wc, int lr, int lg, f32x4 acc[4][4]) {
#pragma unroll
  for (int kk = 0; kk < 2; ++kk) {
    const int cb = kk * 4 + lg;
    f16x8 a[4], b[4];
#pragma unroll
    for (int mi = 0; mi < 4; ++mi) {
      int row = wr * 64 + mi * 16 + lr;
      a[mi] = *(const f16x8*)&CA[row * 64 + ((cb ^ (row & 7)) << 3)];
    }
#pragma unroll
    for (int ni = 0; ni < 4; ++ni) {
      int col = wc * 64 + ni * 16 + lr;
      b[ni] = *(const f16x8*)&CB[col * 64 + ((cb ^ (col & 7)) << 3)];
    }
    __builtin_amdgcn_s_setprio(1);
#pragma unroll
    for (int mi = 0; mi < 4; ++mi)
#pragma unroll
      for (int ni = 0; ni < 4; ++ni)
        acc[mi][ni] = __builtin_amdgcn_mfma_f32_16x16x32_f16(a[mi], b[ni], acc[mi][ni], 0, 0, 0);
    __builtin_amdgcn_s_setprio(0);
  }
}

// base = e^{i*w0*((32s+16g)*t mod V)} — exact integer reduction, no chaining
__device__ __forceinline__ void seed_base(int s, int g, int t, float& br, float& bi) {
  int fb = 32 * s + 16 * g;
  int m = (fb * t) % V_N;                        // fb*t <= 480*50302 < 2^31
  float sn, cs;
  __sincosf((TWO_PI / (float)V_N) * (float)m, &sn, &cs);
  br = cs; bi = sn;
}

__device__ __forceinline__ void gen_bt(const float Tr[16], const float Ti[16],
                                       float br, float bi, f16x8 bt[4]) {
#pragma unroll
  for (int u = 0; u < 4; ++u)
#pragma unroll
    for (int p = 0; p < 4; ++p) {
      const int j = 4 * u + p;
      float re = br * Tr[j] - bi * Ti[j];      // cos(w0*(fb+j+1)*t)
      float im = br * Ti[j] + bi * Tr[j];      // sin(...)
      bt[u][2 * p]     = (f16)re;
      bt[u][2 * p + 1] = (f16)(-im);
    }
}

__device__ __forceinline__ void store_bt(f16* Bs, int nloc, int g, const f16x8 bt[4]) {
#pragma unroll
  for (int u = 0; u < 4; ++u) {
    int c = 4 * g + u;
    *(f16x8*)&Bs[nloc * 64 + ((c ^ (nloc & 7)) << 3)] = bt[u];
  }
}

__global__ __launch_bounds__(256, 3) void k2_otf4(
    const f16* __restrict__ A, float* __restrict__ out) {
  __shared__ __align__(16) f16 As0[128 * 64], As1[128 * 64];
  __shared__ __align__(16) f16 Bs[128 * 64];
  const int tid = threadIdx.x;
  // XCD bijective swizzle (12576 = 8*1572) + by-MAJOR: each XCD owns exactly 4
  // m-panels (1572 = 4*393) -> A L2-resident; adjacent-bx blocks co-resident so
  // partial 128B out-lines merge in L2 before eviction.
  const int orig = blockIdx.x;
  const int wgid = (orig & 7) * 1572 + (orig >> 3);
  const int by = wgid / 393;
  const int bx = wgid - by * 393;
  const int bn0 = bx << 7;
  const int bm0 = by << 7;
  const int lane = tid & 63, wid = tid >> 6;
  const int lr = lane & 15, lg = lane >> 4;
  const int wr = wid >> 1, wc = wid & 1;

  // ---- B-gen init: T[j] = e^{i*w0*((j+1)t mod V)}, all exact-seeded ----
  const int nloc = tid & 127;
  const int g = tid >> 7;
  int t = bn0 + nloc;
  if (t >= V_N) t -= V_N;                       // tail cols alias; never written
  const float w0 = TWO_PI / (float)V_N;
  float Tr[16], Ti[16];
#pragma unroll
  for (int j = 0; j < 16; ++j) {
    int m = ((j + 1) * t) % V_N;
    float sn, cs;
    __sincosf(w0 * (float)m, &sn, &cs);
    Tr[j] = cs; Ti[j] = sn;
  }

  f32x4 acc[4][4];
#pragma unroll
  for (int i = 0; i < 4; ++i)
#pragma unroll
    for (int j = 0; j < 4; ++j) acc[i][j] = (f32x4){0.f, 0.f, 0.f, 0.f};

  // ---- prologue: B(0) -> Bs, A(0) -> As0 ----
  {
    float br, bi;
    seed_base(0, g, t, br, bi);
    f16x8 bt[4];
    gen_bt(Tr, Ti, br, bi, bt);
    store_bt(Bs, nloc, g, bt);
  }
  stage_tile(A, bm0, 0, As0, wid, lane);

  f16x8 btn[4];                                  // next tile's B, in regs
  for (int s = 0; s < 8; ++s) {
    const bool nxt = (s < 7);
    f16* Ac = (s & 1) ? As1 : As0;
    f16* An = (s & 1) ? As0 : As1;
    if (nxt) {
      stage_tile(A, bm0, s + 1, An, wid, lane);  // 4 gloads in flight
      float br, bi;
      seed_base(s + 1, g, t, br, bi);            // exact seed, no chaining
      gen_bt(Tr, Ti, br, bi, btn);               // VALU overlaps gload latency
    }
    asm volatile("s_waitcnt lgkmcnt(0)" ::: "memory");   // B(s) ds_writes drained
    if (nxt) asm volatile("s_waitcnt vmcnt(4)" ::: "memory");  // A(s) landed
    else     asm volatile("s_waitcnt vmcnt(0)" ::: "memory");
    __builtin_amdgcn_s_barrier();
    compute_tile(Ac, Bs, wr, wc, lr, lg, acc);
    asm volatile("" ::: "memory");
    __builtin_amdgcn_s_barrier();                // all waves done reading B(s)
    if (nxt) store_bt(Bs, nloc, g, btn);         // write B(s+1) after the barrier
  }

  const float scale = 2.0f / (float)V_N;
#pragma unroll
  for (int ni = 0; ni < 4; ++ni) {
    int col = bn0 + wc * 64 + ni * 16 + lr;
    if (col < V_N) {
#pragma unroll
      for (int mi = 0; mi < 4; ++mi)
#pragma unroll
        for (int r = 0; r < 4; ++r) {
          int row = bm0 + wr * 64 + mi * 16 + lg * 4 + r;
          out[(size_t)row * V_N + col] = acc[mi][ni][r] * scale;
        }
    }
  }
}

extern "C" void kernel_launch(void* const* d_in, const int* in_sizes, int n_in,
                              void* d_out, int out_size, void* d_ws, size_t ws_size,
                              hipStream_t stream) {
  const float* h = (const float*)d_in[0];
  const float* w = (const float*)d_in[1];
  float* out = (float*)d_out;
  f16* A = (f16*)d_ws;                           // MT*KC*2 = 4.2 MB scratch

  dim3 blk(256);
  hipLaunchKernelGGL(k1_proj, dim3(KC / 64, MT / 64), blk, 0, stream, h, w, A);
  hipLaunchKernelGGL(k2_otf4, dim3(NPAN * 32), blk, 0, stream, A, out);
}